// Round 1
// baseline (944.480 us; speedup 1.0000x reference)
//
#include <hip/hip_runtime.h>

// KnotAttention on MI355X — round 1: correct fp32 vector implementation.
//
// Softmax is over the NODE axis (N=1e5) per (head, slot): needs a global
// sum of exp(logit) per (h,r) -> 2-kernel structure with a 20-float
// accumulator in workspace. Logits are O(|a|<~4) so exp() is overflow-safe
// without max subtraction (identical math to softmax-with-max).
//
// Layout: block = 256 threads = 4 waves; wave == head h, lane == node.
// 64 nodes per block. Per slot r we stage the 64 gathered rows (128 floats
// each) into LDS (row stride 132 floats: 16B-aligned, conflicts only on the
// rare staging writes). Weight indices are wave-uniform (readfirstlane on h)
// so the compiler emits s_load scalar broadcasts -> inner loop is ~1
// ds_read_b128 + 128 v_fma_f32 per 4-d step.

#define N_NODES 100000
#define D 128
#define H 4
#define DK 32
#define DV 32
#define R 5
#define NPB 64            // nodes per block
#define ROW_STRIDE 132    // padded LDS row stride in floats (16B-aligned)
#define THREADS 256

__device__ __forceinline__ void stage_rows(const float* __restrict__ x,
                                           const int* __restrict__ nbr,
                                           int base, int r, float* xs)
{
    // 256 threads stage 64 rows x 128 floats into LDS (4 threads per row).
    const int t = threadIdx.x;
    const int row = t >> 2;   // 0..63
    const int sub = t & 3;    // 0..3
    int node = base + row;
    if (node >= N_NODES) node = N_NODES - 1;  // clamp; results masked later
    int src_node = (r == 0) ? node : nbr[node * 4 + (r - 1)];
    const float4* src = (const float4*)(x + src_node * D);
    float4* dst = (float4*)(xs + row * ROW_STRIDE);
#pragma unroll
    for (int i = 0; i < 8; ++i) {
        dst[sub + i * 4] = src[sub + i * 4];
    }
}

__global__ __launch_bounds__(THREADS, 2)
void knot_logits(const float* __restrict__ x,
                 const int* __restrict__ nbr,
                 const float* __restrict__ w_q,
                 const float* __restrict__ w_k,
                 float* __restrict__ e_out,   // (H*R, N)
                 float* __restrict__ sums)    // 20 floats, pre-zeroed
{
    __shared__ __align__(16) float xs[NPB * ROW_STRIDE];
    const int base = blockIdx.x * NPB;
    const int lane = threadIdx.x & 63;
    const int h = __builtin_amdgcn_readfirstlane((int)(threadIdx.x >> 6));
    const int node = base + lane;
    const bool valid = node < N_NODES;

    float Q[DK];
    float acc[DK];

    // ---- phase 0: stage self rows, compute Q ----
    stage_rows(x, nbr, base, 0, xs);
    __syncthreads();
    {
        const float* wq = w_q + h * (D * DK);
#pragma unroll
        for (int k = 0; k < DK; ++k) Q[k] = 0.f;
        const float4* xrow = (const float4*)(xs + lane * ROW_STRIDE);
#pragma unroll 2
        for (int dq = 0; dq < D / 4; ++dq) {
            float4 xv = xrow[dq];
            const float* w0 = wq + dq * 4 * DK;
#pragma unroll
            for (int k = 0; k < DK; ++k) {
                Q[k] += xv.x * w0[k] + xv.y * w0[DK + k]
                      + xv.z * w0[2 * DK + k] + xv.w * w0[3 * DK + k];
            }
        }
    }

    // ---- per-slot: K, logit, exp, global-sum contribution ----
#pragma unroll 1
    for (int r = 0; r < R; ++r) {
        if (r > 0) {
            __syncthreads();                 // protect previous phase reads
            stage_rows(x, nbr, base, r, xs); // neighbor rows
            __syncthreads();
        }
        const float* wk = w_k + (h * R + r) * (D * DK);
#pragma unroll
        for (int k = 0; k < DK; ++k) acc[k] = 0.f;
        const float4* xrow = (const float4*)(xs + lane * ROW_STRIDE);
#pragma unroll 2
        for (int dq = 0; dq < D / 4; ++dq) {
            float4 xv = xrow[dq];
            const float* w0 = wk + dq * 4 * DK;
#pragma unroll
            for (int k = 0; k < DK; ++k) {
                acc[k] += xv.x * w0[k] + xv.y * w0[DK + k]
                        + xv.z * w0[2 * DK + k] + xv.w * w0[3 * DK + k];
            }
        }
        float logit = 0.f;
#pragma unroll
        for (int k = 0; k < DK; ++k) logit += Q[k] * acc[k];
        // 1/sqrt(32)
        float e = valid ? __expf(logit * 0.17677669529663688f) : 0.f;
        if (valid) e_out[(h * R + r) * N_NODES + node] = e;

        // wave-64 reduction -> one atomic per wave per slot
        float s = e;
#pragma unroll
        for (int off = 32; off > 0; off >>= 1) s += __shfl_xor(s, off, 64);
        if (lane == 0) atomicAdd(&sums[h * R + r], s);
    }
}

__global__ __launch_bounds__(THREADS, 2)
void knot_out(const float* __restrict__ x,
              const int* __restrict__ nbr,
              const float* __restrict__ w_v,
              const float* __restrict__ e_in,  // (H*R, N)
              const float* __restrict__ sums,  // 20
              float* __restrict__ out)         // (N, H*DV)
{
    __shared__ __align__(16) float xs[NPB * ROW_STRIDE];
    const int base = blockIdx.x * NPB;
    const int lane = threadIdx.x & 63;
    const int h = __builtin_amdgcn_readfirstlane((int)(threadIdx.x >> 6));
    const int node = base + lane;
    const bool valid = node < N_NODES;

    float Z[DV];
    float acc[DV];
#pragma unroll
    for (int v = 0; v < DV; ++v) Z[v] = 0.f;

#pragma unroll 1
    for (int r = 0; r < R; ++r) {
        if (r > 0) __syncthreads();
        stage_rows(x, nbr, base, r, xs);
        __syncthreads();

        const float* wv = w_v + (h * R + r) * (D * DV);
#pragma unroll
        for (int v = 0; v < DV; ++v) acc[v] = 0.f;
        const float4* xrow = (const float4*)(xs + lane * ROW_STRIDE);
#pragma unroll 2
        for (int dq = 0; dq < D / 4; ++dq) {
            float4 xv = xrow[dq];
            const float* w0 = wv + dq * 4 * DV;
#pragma unroll
            for (int v = 0; v < DV; ++v) {
                acc[v] += xv.x * w0[v] + xv.y * w0[DV + v]
                        + xv.z * w0[2 * DV + v] + xv.w * w0[3 * DV + v];
            }
        }
        float wgt = 0.f;
        if (valid) wgt = e_in[(h * R + r) * N_NODES + node] / sums[h * R + r];
#pragma unroll
        for (int v = 0; v < DV; ++v) Z[v] += wgt * acc[v];
    }

    // ---- transpose through LDS, coalesced float4 stores ----
    __syncthreads();   // protect last phase's xs reads
    {
        float4* dst = (float4*)(xs + lane * ROW_STRIDE + h * DV);
#pragma unroll
        for (int vq = 0; vq < DV / 4; ++vq)
            dst[vq] = make_float4(Z[vq * 4], Z[vq * 4 + 1],
                                  Z[vq * 4 + 2], Z[vq * 4 + 3]);
    }
    __syncthreads();
    {
        const int t = threadIdx.x;
#pragma unroll
        for (int i = 0; i < 8; ++i) {
            int fidx = t * 4 + i * 1024;   // float index within 64x128 tile
            int row = fidx >> 7;
            int dcol = fidx & 127;
            if (base + row < N_NODES) {
                float4 val = *(const float4*)(xs + row * ROW_STRIDE + dcol);
                *(float4*)(out + (base + row) * D + dcol) = val;
            }
        }
    }
}

extern "C" void kernel_launch(void* const* d_in, const int* in_sizes, int n_in,
                              void* d_out, int out_size, void* d_ws, size_t ws_size,
                              hipStream_t stream)
{
    const float* x   = (const float*)d_in[0];
    const int*   nbr = (const int*)d_in[1];   // (N,4) int32 per harness contract
    const float* w_q = (const float*)d_in[2];
    const float* w_k = (const float*)d_in[3];
    const float* w_v = (const float*)d_in[4];
    float* out = (float*)d_out;

    float* sums = (float*)d_ws;          // 20 floats (padded to 32)
    float* e    = (float*)d_ws + 32;     // H*R*N floats = 8 MB

    hipMemsetAsync(sums, 0, 32 * sizeof(float), stream);

    const int blocks = (N_NODES + NPB - 1) / NPB;   // 1563
    knot_logits<<<blocks, THREADS, 0, stream>>>(x, nbr, w_q, w_k, e, sums);
    knot_out<<<blocks, THREADS, 0, stream>>>(x, nbr, w_v, e, sums, out);
}

// Round 2
// 250.883 us; speedup vs baseline: 3.7646x; 3.7646x over previous
//
#include <hip/hip_runtime.h>

// KnotAttention MI355X — round 2: split-bf16 MFMA (hh+hl+lh => ~fp32 accuracy).
//
// Transposed GEMM form: C^T[kout][node] = W^T @ X^T per (head, slot).
//   A-operand = W^T (M=32=kout), pre-packed into per-lane fragments in ws.
//   B-operand = X^T (N=64 nodes), from XOR-swizzled LDS bf16 hi/lo tiles.
//   K=128 (d), 4 k-steps of 32.
// C/D layout: col(lane&15)=node-dim(n), row((lane>>4)*4+reg)=kout-dim(m).
// Q and K come out in the SAME layout -> logit dot = in-lane products +
// shfl_xor(16,32). V scaled by per-node softmax weight in-register.
// Softmax is over the NODE axis: global sums via 64-way-spread atomics,
// reduced by a tiny kernel between the two main kernels. e stored as fp16.

#define N_NODES 100000
#define D 128
#define H 4
#define R 5
#define NPB 64
#define THREADS 256
#define NBLOCKS ((N_NODES + NPB - 1) / NPB)

typedef __attribute__((ext_vector_type(8))) __bf16 bf16x8;
typedef __attribute__((ext_vector_type(4))) float f32x4;
typedef _Float16 half_t;

// ---------------- weight prep: pack A-fragments (hi/lo split) ----------------
// 44 matrices (4 wq + 20 wk + 20 wv), each 128x32 -> 8 frags (mt*4+kt) of
// 64 lanes x 8 bf16:  blob[m*4096 + f*512 + lane*8 + j]
//   = W[d = kt*32 + (lane>>4)*8 + j][kout = mt*16 + (lane&15)]
__global__ void knot_prep(const float* __restrict__ wq,
                          const float* __restrict__ wk,
                          const float* __restrict__ wv,
                          __bf16* __restrict__ wph, __bf16* __restrict__ wplo)
{
    const int m = blockIdx.x;  // 0..43
    const float* src = (m < 4) ? (wq + m * 4096)
                     : (m < 24) ? (wk + (m - 4) * 4096)
                                : (wv + (m - 24) * 4096);
    const int t = threadIdx.x;
#pragma unroll
    for (int i = 0; i < 16; ++i) {
        int p = t * 16 + i;               // 0..4095
        int j = p & 7;
        int ln = (p >> 3) & 63;
        int f = p >> 9;                   // mt*4 + kt
        int kt = f & 3, mt = f >> 2;
        int d = kt * 32 + (ln >> 4) * 8 + j;
        int ko = mt * 16 + (ln & 15);
        float v = src[d * 32 + ko];
        __bf16 hb = (__bf16)v;
        wph[m * 4096 + p] = hb;
        wplo[m * 4096 + p] = (__bf16)(v - (float)hb);
    }
}

// ------------- stage gathered x rows as bf16 hi/lo, XOR-quad swizzle ---------
// tile: 64 rows x 128 bf16, row stride 256B; quad (16B) kq stored at kq^(row&7)
__device__ __forceinline__ void stage_tile(const float* __restrict__ x,
                                           const int* __restrict__ nbr,
                                           int base, int r,
                                           __bf16* xhi, __bf16* xlo)
{
    const int t = threadIdx.x;
    const int row = t >> 2;
    const int c = t & 3;
    int node = base + row;
    if (node >= N_NODES) node = N_NODES - 1;    // clamp; masked downstream
    int src = (r == 0) ? node : nbr[node * 4 + (r - 1)];
    const float4* srcp = (const float4*)(x + (size_t)src * D);
#pragma unroll
    for (int i = 0; i < 4; ++i) {
        int kq = c + 4 * i;                     // quad 0..15
        float4 v0 = srcp[kq * 2];
        float4 v1 = srcp[kq * 2 + 1];
        float f[8] = {v0.x, v0.y, v0.z, v0.w, v1.x, v1.y, v1.z, v1.w};
        bf16x8 hv, lv;
#pragma unroll
        for (int j = 0; j < 8; ++j) {
            __bf16 hb = (__bf16)f[j];
            hv[j] = hb;
            lv[j] = (__bf16)(f[j] - (float)hb);
        }
        int sq = kq ^ (row & 7);
        *(bf16x8*)(xhi + row * 128 + sq * 8) = hv;
        *(bf16x8*)(xlo + row * 128 + sq * 8) = lv;
    }
}

// ---- one 32x64 projection (K=128) in split-bf16: acc[mt][nt], 96 MFMAs -----
__device__ __forceinline__ void compute_proj(int mid,
                                             const __bf16* __restrict__ wph,
                                             const __bf16* __restrict__ wplo,
                                             const __bf16* xhi, const __bf16* xlo,
                                             int lane, f32x4 (&acc)[2][4])
{
    const int l15 = lane & 15;
    const int q = (lane >> 4) & 3;
#pragma unroll
    for (int mt = 0; mt < 2; ++mt)
#pragma unroll
        for (int nt = 0; nt < 4; ++nt)
            acc[mt][nt] = (f32x4){0.f, 0.f, 0.f, 0.f};

#pragma unroll
    for (int kt = 0; kt < 4; ++kt) {
        bf16x8 ah[2], al[2];
#pragma unroll
        for (int mt = 0; mt < 2; ++mt) {
            int off = mid * 4096 + (mt * 4 + kt) * 512 + lane * 8;
            ah[mt] = *(const bf16x8*)(wph + off);
            al[mt] = *(const bf16x8*)(wplo + off);
        }
#pragma unroll
        for (int nt = 0; nt < 4; ++nt) {
            int brow = nt * 16 + l15;
            int boff = brow * 128 + (((kt * 4 + q) ^ (l15 & 7)) * 8);
            bf16x8 bh = *(const bf16x8*)(xhi + boff);
            bf16x8 bl = *(const bf16x8*)(xlo + boff);
#pragma unroll
            for (int mt = 0; mt < 2; ++mt) {
                acc[mt][nt] = __builtin_amdgcn_mfma_f32_16x16x32_bf16(ah[mt], bh, acc[mt][nt], 0, 0, 0);
                acc[mt][nt] = __builtin_amdgcn_mfma_f32_16x16x32_bf16(ah[mt], bl, acc[mt][nt], 0, 0, 0);
                acc[mt][nt] = __builtin_amdgcn_mfma_f32_16x16x32_bf16(al[mt], bh, acc[mt][nt], 0, 0, 0);
            }
        }
    }
}

// --------------------------- kernel 1: Q,K -> e, sums ------------------------
__global__ __launch_bounds__(THREADS, 3)
void knot_logits(const float* __restrict__ x, const int* __restrict__ nbr,
                 const __bf16* __restrict__ wph, const __bf16* __restrict__ wplo,
                 half_t* __restrict__ eh, float* __restrict__ sums_p)
{
    __shared__ __align__(16) __bf16 xhi[NPB * 128];
    __shared__ __align__(16) __bf16 xlo[NPB * 128];
    const int base = blockIdx.x * NPB;
    const int lane = threadIdx.x & 63;
    const int h = __builtin_amdgcn_readfirstlane((int)(threadIdx.x >> 6));
    const int l15 = lane & 15;
    const int q = (lane >> 4) & 3;

    stage_tile(x, nbr, base, 0, xhi, xlo);
    __syncthreads();

    f32x4 qf[2][4];
    compute_proj(h, wph, wplo, xhi, xlo, lane, qf);   // Q (matrix id h)

    f32x4 kf[2][4];
#pragma unroll 1
    for (int r = 0; r < R; ++r) {
        if (r > 0) {
            __syncthreads();
            stage_tile(x, nbr, base, r, xhi, xlo);
            __syncthreads();
        }
        compute_proj(4 + h * 5 + r, wph, wplo, xhi, xlo, lane, kf);

        float esum = 0.f;
#pragma unroll
        for (int nt = 0; nt < 4; ++nt) {
            float p = 0.f;
#pragma unroll
            for (int mt = 0; mt < 2; ++mt)
#pragma unroll
                for (int j = 0; j < 4; ++j)
                    p += qf[mt][nt][j] * kf[mt][nt][j];
            p += __shfl_xor(p, 16, 64);
            p += __shfl_xor(p, 32, 64);
            int node = base + nt * 16 + l15;
            float e = (node < N_NODES) ? __expf(p * 0.17677669529663688f) : 0.f;
            if (q == 0 && node < N_NODES)
                eh[(size_t)(h * 5 + r) * N_NODES + node] = (half_t)e;
            esum += e;
        }
        esum += __shfl_xor(esum, 1, 64);
        esum += __shfl_xor(esum, 2, 64);
        esum += __shfl_xor(esum, 4, 64);
        esum += __shfl_xor(esum, 8, 64);
        if (lane == 0)
            atomicAdd(&sums_p[(h * 5 + r) * 64 + (blockIdx.x & 63)], esum);
    }
}

// ------------------- tiny reduce: sums_p[20][64] -> sums[20] -----------------
__global__ void knot_reduce(const float* __restrict__ sums_p, float* __restrict__ sums)
{
    const int w = threadIdx.x >> 6;
    const int lane = threadIdx.x & 63;
#pragma unroll
    for (int i = 0; i < 5; ++i) {
        int hr = w * 5 + i;
        float v = sums_p[hr * 64 + lane];
        v += __shfl_xor(v, 1, 64);
        v += __shfl_xor(v, 2, 64);
        v += __shfl_xor(v, 4, 64);
        v += __shfl_xor(v, 8, 64);
        v += __shfl_xor(v, 16, 64);
        v += __shfl_xor(v, 32, 64);
        if (lane == 0) sums[hr] = v;
    }
}

// --------------------------- kernel 2: V -> Z -> out -------------------------
__global__ __launch_bounds__(THREADS, 3)
void knot_out(const float* __restrict__ x, const int* __restrict__ nbr,
              const __bf16* __restrict__ wph, const __bf16* __restrict__ wplo,
              const half_t* __restrict__ eh, const float* __restrict__ sums,
              float* __restrict__ out)
{
    __shared__ __align__(16) unsigned char lds_raw[4 * 32 * 68 * 4]; // 34816 B
    __bf16* xhi = (__bf16*)lds_raw;
    __bf16* xlo = xhi + NPB * 128;
    const int base = blockIdx.x * NPB;
    const int lane = threadIdx.x & 63;
    const int h = __builtin_amdgcn_readfirstlane((int)(threadIdx.x >> 6));
    const int l15 = lane & 15;
    const int q = (lane >> 4) & 3;

    f32x4 z[2][4];
#pragma unroll
    for (int mt = 0; mt < 2; ++mt)
#pragma unroll
        for (int nt = 0; nt < 4; ++nt)
            z[mt][nt] = (f32x4){0.f, 0.f, 0.f, 0.f};

    f32x4 vf[2][4];
#pragma unroll 1
    for (int r = 0; r < R; ++r) {
        if (r > 0) __syncthreads();
        stage_tile(x, nbr, base, r, xhi, xlo);
        __syncthreads();
        compute_proj(24 + h * 5 + r, wph, wplo, xhi, xlo, lane, vf);

        float inv = 1.0f / sums[h * 5 + r];
        float w[4];
#pragma unroll
        for (int nt = 0; nt < 4; ++nt) {
            int node = base + nt * 16 + l15;
            if (node >= N_NODES) node = N_NODES - 1;   // clamped; masked at store
            w[nt] = (float)eh[(size_t)(h * 5 + r) * N_NODES + node] * inv;
        }
#pragma unroll
        for (int mt = 0; mt < 2; ++mt)
#pragma unroll
            for (int nt = 0; nt < 4; ++nt)
#pragma unroll
                for (int j = 0; j < 4; ++j)
                    z[mt][nt][j] += w[nt] * vf[mt][nt][j];
    }

    // epilogue: transpose Z^T[v][node] through LDS -> coalesced float4 stores
    __syncthreads();
    float* zt = (float*)lds_raw;   // [head][32 v][stride 68]
#pragma unroll
    for (int mt = 0; mt < 2; ++mt)
#pragma unroll
        for (int nt = 0; nt < 4; ++nt)
#pragma unroll
            for (int j = 0; j < 4; ++j) {
                int v = mt * 16 + q * 4 + j;
                zt[h * 2176 + v * 68 + nt * 16 + l15] = z[mt][nt][j];
            }
    __syncthreads();
    {
        const int row = threadIdx.x >> 2;   // node_local
        const int c = threadIdx.x & 3;      // 32-col chunk == head
        if (base + row < N_NODES) {
            float* dst = out + (size_t)(base + row) * D + c * 32;
#pragma unroll
            for (int i = 0; i < 8; ++i) {
                float4 val;
                val.x = zt[c * 2176 + (i * 4 + 0) * 68 + row];
                val.y = zt[c * 2176 + (i * 4 + 1) * 68 + row];
                val.z = zt[c * 2176 + (i * 4 + 2) * 68 + row];
                val.w = zt[c * 2176 + (i * 4 + 3) * 68 + row];
                *(float4*)(dst + i * 4) = val;
            }
        }
    }
}

// --------------------------------- launcher ---------------------------------
// ws layout (bytes): [0,128)=sums  [128,5248)=sums_p[20*64]
//                    [5248, +4e6)=e fp16[20*N]
//                    then wpack_hi[44*4096 bf16], wpack_lo  (total ~4.73 MB)
extern "C" void kernel_launch(void* const* d_in, const int* in_sizes, int n_in,
                              void* d_out, int out_size, void* d_ws, size_t ws_size,
                              hipStream_t stream)
{
    const float* x   = (const float*)d_in[0];
    const int*   nbr = (const int*)d_in[1];
    const float* w_q = (const float*)d_in[2];
    const float* w_k = (const float*)d_in[3];
    const float* w_v = (const float*)d_in[4];
    float* out = (float*)d_out;

    float*   sums   = (float*)d_ws;
    float*   sums_p = sums + 32;
    half_t*  eh     = (half_t*)((char*)d_ws + 5248);
    __bf16*  wph    = (__bf16*)((char*)d_ws + 5248 + 4000000);
    __bf16*  wplo   = wph + 44 * 4096;

    hipMemsetAsync(d_ws, 0, 5248, stream);
    knot_prep<<<44, THREADS, 0, stream>>>(w_q, w_k, w_v, wph, wplo);
    knot_logits<<<NBLOCKS, THREADS, 0, stream>>>(x, nbr, wph, wplo, eh, sums_p);
    knot_reduce<<<1, THREADS, 0, stream>>>(sums_p, sums);
    knot_out<<<NBLOCKS, THREADS, 0, stream>>>(x, nbr, wph, wplo, eh, sums, out);
}

// Round 3
// 222.675 us; speedup vs baseline: 4.2415x; 1.1267x over previous
//
#include <hip/hip_runtime.h>

// KnotAttention MI355X — round 3: single-term fp16 MFMA + async staging.
//
// Numerics: fp16 (u=2^-11) on both x and w gives ~4x better error than
// bf16+lo-term splitting, at 1 MFMA per term: 32 MFMAs of 16x16x32_f16 per
// 32x64x128 projection. x pre-converted to fp16 once (prep_x); weights
// pre-packed into per-lane A-fragments (prep_w).
//
// Staging: __builtin_amdgcn_global_load_lds width=16, XOR-quad swizzle
// applied on the GLOBAL side so the LDS dest is uniform_base + lane*16
// (hardware requirement). Tile: 64 rows x 128 f16 (256B/row), quad kq of
// row stored at position kq^(row&7) -> conflict-free b128 reads.
//
// Softmax over the NODE axis (N=1e5): spread atomics -> tiny reduce kernel.

#define N_NODES 100000
#define D 128
#define H 4
#define R 5
#define NPB 64
#define THREADS 256
#define NBLOCKS ((N_NODES + NPB - 1) / NPB)

typedef _Float16 half_t;
typedef __attribute__((ext_vector_type(8))) _Float16 f16x8;
typedef __attribute__((ext_vector_type(4))) float f32x4;

typedef const __attribute__((address_space(1))) unsigned int* gp_t;
typedef __attribute__((address_space(3))) unsigned int* lp_t;

__device__ __forceinline__ void async_copy16(const void* g, void* l) {
    __builtin_amdgcn_global_load_lds((gp_t)g, (lp_t)l, 16, 0, 0);
}

// ------------------------- prep: x (f32) -> xh (f16) -------------------------
__global__ void prep_x(const float* __restrict__ x, half_t* __restrict__ xh)
{
    const int total = N_NODES * D / 8;   // 1.6M groups of 8
    for (int i = blockIdx.x * blockDim.x + threadIdx.x; i < total;
         i += gridDim.x * blockDim.x) {
        const float4* s = (const float4*)x + (size_t)i * 2;
        float4 a = s[0], b = s[1];
        f16x8 h = {(half_t)a.x, (half_t)a.y, (half_t)a.z, (half_t)a.w,
                   (half_t)b.x, (half_t)b.y, (half_t)b.z, (half_t)b.w};
        *((f16x8*)xh + i) = h;
    }
}

// ----------------- prep: pack 44 weight mats into A-fragments ----------------
// blob[m*4096 + (mt*4+kt)*512 + lane*8 + j] = W[d=kt*32+(lane>>4)*8+j][kout=mt*16+(lane&15)]
__global__ void prep_w(const float* __restrict__ wq, const float* __restrict__ wk,
                       const float* __restrict__ wv, half_t* __restrict__ wph)
{
    const int m = blockIdx.x;  // 0..43
    const float* src = (m < 4) ? (wq + m * 4096)
                     : (m < 24) ? (wk + (m - 4) * 4096)
                                : (wv + (m - 24) * 4096);
    const int t = threadIdx.x;
#pragma unroll
    for (int i = 0; i < 16; ++i) {
        int p = t * 16 + i;
        int j = p & 7, ln = (p >> 3) & 63, f = p >> 9;
        int kt = f & 3, mt = f >> 2;
        int d = kt * 32 + (ln >> 4) * 8 + j;
        int ko = mt * 16 + (ln & 15);
        wph[m * 4096 + p] = (half_t)src[d * 32 + ko];
    }
}

// ---------------- stage 64 gathered rows via global_load_lds -----------------
__device__ __forceinline__ void stage_tile(const half_t* __restrict__ xh,
                                           const int* __restrict__ nbr,
                                           int base, int r, char* tile)
{
    const int w = threadIdx.x >> 6;
    const int lane = threadIdx.x & 63;
    const int rr = lane >> 4, c = lane & 15;
#pragma unroll
    for (int i = 0; i < 4; ++i) {
        int row0 = w * 16 + i * 4;            // wave-uniform
        int row = row0 + rr;
        int node = base + row;
        if (node >= N_NODES) node = N_NODES - 1;
        int src = (r == 0) ? node : nbr[node * 4 + (r - 1)];
        const char* g = (const char*)xh + (size_t)src * 256 + ((c ^ (row & 7)) << 4);
        async_copy16(g, tile + row0 * 256);   // lds dest = base + lane*16
    }
}

// ------ one 32(kout) x 64(node) x 128(d) projection: 32 MFMAs, 16 b128 -------
__device__ __forceinline__ void proj(int mid, const half_t* __restrict__ wph,
                                     const half_t* tile, int lane,
                                     f32x4 (&acc)[2][4])
{
    const int l15 = lane & 15;
    const int q = lane >> 4;
#pragma unroll
    for (int mt = 0; mt < 2; ++mt)
#pragma unroll
        for (int nt = 0; nt < 4; ++nt)
            acc[mt][nt] = (f32x4){0.f, 0.f, 0.f, 0.f};

#pragma unroll
    for (int kt = 0; kt < 4; ++kt) {
        f16x8 a0 = *(const f16x8*)(wph + ((mid * 8 + kt) * 64 + lane) * 8);
        f16x8 a1 = *(const f16x8*)(wph + ((mid * 8 + 4 + kt) * 64 + lane) * 8);
#pragma unroll
        for (int nt = 0; nt < 4; ++nt) {
            int row = nt * 16 + l15;
            int sq = (kt * 4 + q) ^ (row & 7);
            f16x8 b = *(const f16x8*)(tile + row * 128 + sq * 8);
            acc[0][nt] = __builtin_amdgcn_mfma_f32_16x16x32_f16(a0, b, acc[0][nt], 0, 0, 0);
            acc[1][nt] = __builtin_amdgcn_mfma_f32_16x16x32_f16(a1, b, acc[1][nt], 0, 0, 0);
        }
    }
}

// --------------------------- kernel 1: Q,K -> e, sums ------------------------
__global__ __launch_bounds__(THREADS, 3)
void knot_logits(const half_t* __restrict__ xh, const int* __restrict__ nbr,
                 const half_t* __restrict__ wph,
                 half_t* __restrict__ eh, float* __restrict__ sums_p)
{
    __shared__ __align__(16) char smem[NPB * 256];   // 16 KB f16 tile
    half_t* tile = (half_t*)smem;
    const int base = blockIdx.x * NPB;
    const int lane = threadIdx.x & 63;
    const int h = __builtin_amdgcn_readfirstlane((int)(threadIdx.x >> 6));
    const int l15 = lane & 15;

    stage_tile(xh, nbr, base, 0, smem);
    __syncthreads();                                  // drains vmcnt(0)

    f32x4 qf[2][4];
    proj(h, wph, tile, lane, qf);                     // Q (mats 0..3)

    f32x4 kf[2][4];
#pragma unroll 1
    for (int r = 0; r < R; ++r) {
        if (r > 0) {
            __syncthreads();
            stage_tile(xh, nbr, base, r, smem);
            __syncthreads();
        }
        proj(4 + h * 5 + r, wph, tile, lane, kf);     // K (mats 4..23)

        float esum = 0.f;
#pragma unroll
        for (int nt = 0; nt < 4; ++nt) {
            float p = 0.f;
#pragma unroll
            for (int mt = 0; mt < 2; ++mt)
#pragma unroll
                for (int j = 0; j < 4; ++j)
                    p += qf[mt][nt][j] * kf[mt][nt][j];
            p += __shfl_xor(p, 16, 64);
            p += __shfl_xor(p, 32, 64);
            int node = base + nt * 16 + l15;
            float e = (node < N_NODES) ? __expf(p * 0.17677669529663688f) : 0.f;
            if ((lane >> 4) == 0 && node < N_NODES)
                eh[(size_t)(h * 5 + r) * N_NODES + node] = (half_t)e;
            esum += e;
        }
        // each 16-lane group holds the identical partial sum after xor 1..8
        esum += __shfl_xor(esum, 1, 64);
        esum += __shfl_xor(esum, 2, 64);
        esum += __shfl_xor(esum, 4, 64);
        esum += __shfl_xor(esum, 8, 64);
        if (lane == 0)
            atomicAdd(&sums_p[(h * 5 + r) * 64 + (blockIdx.x & 63)], esum);
    }
}

// ------------------- tiny reduce: sums_p[20][64] -> sums[20] -----------------
__global__ void knot_reduce(const float* __restrict__ sums_p, float* __restrict__ sums)
{
    const int w = threadIdx.x >> 6;
    const int lane = threadIdx.x & 63;
#pragma unroll
    for (int i = 0; i < 5; ++i) {
        int hr = w * 5 + i;
        float v = sums_p[hr * 64 + lane];
        v += __shfl_xor(v, 1, 64);
        v += __shfl_xor(v, 2, 64);
        v += __shfl_xor(v, 4, 64);
        v += __shfl_xor(v, 8, 64);
        v += __shfl_xor(v, 16, 64);
        v += __shfl_xor(v, 32, 64);
        if (lane == 0) sums[hr] = v;
    }
}

// --------------------------- kernel 2: V -> Z -> out -------------------------
// epilogue zt strides: VS=67 floats (odd -> v=16 offset != 0 mod 32),
// head-local HS=2152; all LDS accesses <=2-way.
#define VS 67
#define HS 2152
__global__ __launch_bounds__(THREADS, 3)
void knot_out(const half_t* __restrict__ xh, const int* __restrict__ nbr,
              const half_t* __restrict__ wph,
              const half_t* __restrict__ eh, const float* __restrict__ sums,
              float* __restrict__ out)
{
    __shared__ __align__(16) char smem[2 * HS * 4];  // 17216 B >= 16 KB tile
    half_t* tile = (half_t*)smem;
    const int base = blockIdx.x * NPB;
    const int lane = threadIdx.x & 63;
    const int h = __builtin_amdgcn_readfirstlane((int)(threadIdx.x >> 6));
    const int l15 = lane & 15;
    const int q = lane >> 4;

    f32x4 z[2][4];
#pragma unroll
    for (int mt = 0; mt < 2; ++mt)
#pragma unroll
        for (int nt = 0; nt < 4; ++nt)
            z[mt][nt] = (f32x4){0.f, 0.f, 0.f, 0.f};

    f32x4 vf[2][4];
#pragma unroll 1
    for (int r = 0; r < R; ++r) {
        if (r > 0) __syncthreads();
        stage_tile(xh, nbr, base, r, smem);
        __syncthreads();
        proj(24 + h * 5 + r, wph, tile, lane, vf);    // V (mats 24..43)

        float inv = 1.0f / sums[h * 5 + r];
#pragma unroll
        for (int nt = 0; nt < 4; ++nt) {
            int node = base + nt * 16 + l15;
            if (node >= N_NODES) node = N_NODES - 1;
            float w = (float)eh[(size_t)(h * 5 + r) * N_NODES + node] * inv;
#pragma unroll
            for (int mt = 0; mt < 2; ++mt)
#pragma unroll
                for (int j = 0; j < 4; ++j)
                    z[mt][nt][j] += w * vf[mt][nt][j];
        }
    }

    // -------- epilogue: 2 passes of 2 heads through LDS, coalesced out -------
    __syncthreads();
    float* zt = (float*)smem;
#pragma unroll 1
    for (int pass = 0; pass < 2; ++pass) {
        if (pass) __syncthreads();
        if ((h >> 1) == pass) {
#pragma unroll
            for (int mt = 0; mt < 2; ++mt)
#pragma unroll
                for (int nt = 0; nt < 4; ++nt)
#pragma unroll
                    for (int j = 0; j < 4; ++j) {
                        int v = mt * 16 + q * 4 + j;
                        zt[(h & 1) * HS + v * VS + nt * 16 + l15] = z[mt][nt][j];
                    }
        }
        __syncthreads();
        const int row = threadIdx.x >> 2;   // 0..63
        const int c = threadIdx.x & 3;      // 16-col chunk within 64-col half
        if (base + row < N_NODES) {
            float* dst = out + (size_t)(base + row) * D + pass * 64 + c * 16;
#pragma unroll
            for (int i4 = 0; i4 < 4; ++i4) {
                float4 v4;
#pragma unroll
                for (int e = 0; e < 4; ++e) {
                    int col = c * 16 + i4 * 4 + e;   // 0..63
                    int h2 = col >> 5, v = col & 31;
                    ((float*)&v4)[e] = zt[h2 * HS + v * VS + row];
                }
                *(float4*)(dst + i4 * 4) = v4;
            }
        }
    }
}

// --------------------------------- launcher ---------------------------------
// ws layout (bytes):
//   [0,128)        sums[20] (padded)
//   [128,5248)     sums_p[20*64]
//   [8192, +4e6)   eh  f16[20*N]
//   [4,194,304, +360448)  wph f16[44*4096]
//   [4,718,592, +25.6e6)  xh  f16[N*128]          total ~30.3 MB
extern "C" void kernel_launch(void* const* d_in, const int* in_sizes, int n_in,
                              void* d_out, int out_size, void* d_ws, size_t ws_size,
                              hipStream_t stream)
{
    const float* x   = (const float*)d_in[0];
    const int*   nbr = (const int*)d_in[1];
    const float* w_q = (const float*)d_in[2];
    const float* w_k = (const float*)d_in[3];
    const float* w_v = (const float*)d_in[4];
    float* out = (float*)d_out;

    float*  sums   = (float*)d_ws;
    float*  sums_p = sums + 32;
    half_t* eh     = (half_t*)((char*)d_ws + 8192);
    half_t* wph    = (half_t*)((char*)d_ws + 4194304);
    half_t* xh     = (half_t*)((char*)d_ws + 4718592);

    hipMemsetAsync(d_ws, 0, 5248, stream);
    prep_x<<<2048, THREADS, 0, stream>>>(x, xh);
    prep_w<<<44, THREADS, 0, stream>>>(w_q, w_k, w_v, wph);
    knot_logits<<<NBLOCKS, THREADS, 0, stream>>>(xh, nbr, wph, eh, sums_p);
    knot_reduce<<<1, THREADS, 0, stream>>>(sums_p, sums);
    knot_out<<<NBLOCKS, THREADS, 0, stream>>>(xh, nbr, wph, eh, sums, out);
}

// Round 4
// 205.616 us; speedup vs baseline: 4.5934x; 1.0830x over previous
//
#include <hip/hip_runtime.h>

// KnotAttention MI355X — round 4: true double-buffered gather prefetch.
//
// Round-3 autopsy: stage->barrier exposed full gather latency every slot
// (all pipes <15% busy). Fix: two LDS tile buffers (distinct symbols so AA
// can disambiguate DMA writes from ds_reads), prefetch slot r+1 during
// slot r's MFMA work, ONE barrier per slot. vmcnt is in-order, so all
// register loads a slot consumes (A-frags, e-weights) are issued BEFORE
// the prefetch DMAs -> consuming them never drains the prefetch.
// Neighbor indices hoisted to int4 regs at block start. prep_w folded into
// prep_x; softmax-sum reduce folded into knot_out (redundant per block).

#define N_NODES 100000
#define D 128
#define H 4
#define R 5
#define NPB 64
#define THREADS 256
#define NBLOCKS ((N_NODES + NPB - 1) / NPB)

typedef _Float16 half_t;
typedef __attribute__((ext_vector_type(8))) _Float16 f16x8;
typedef __attribute__((ext_vector_type(4))) float f32x4;

typedef const __attribute__((address_space(1))) unsigned int* gp_t;
typedef __attribute__((address_space(3))) unsigned int* lp_t;

__device__ __forceinline__ void async_copy16(const void* g, void* l) {
    __builtin_amdgcn_global_load_lds((gp_t)g, (lp_t)l, 16, 0, 0);
}

template<int V> struct ic { static constexpr int value = V; };

// ---------------- prep: weights -> A-frags, x -> f16 (one kernel) -----------
__global__ void prep(const float* __restrict__ x,
                     const float* __restrict__ wq, const float* __restrict__ wk,
                     const float* __restrict__ wv,
                     half_t* __restrict__ xh, half_t* __restrict__ wph)
{
    const int bid = blockIdx.x;
    const int t = threadIdx.x;
    if (bid < 44) {
        const float* src = (bid < 4) ? (wq + bid * 4096)
                         : (bid < 24) ? (wk + (bid - 4) * 4096)
                                      : (wv + (bid - 24) * 4096);
#pragma unroll
        for (int i = 0; i < 16; ++i) {
            int p = t * 16 + i;
            int j = p & 7, ln = (p >> 3) & 63, f = p >> 9;
            int kt = f & 3, mt = f >> 2;
            int d = kt * 32 + (ln >> 4) * 8 + j;
            int ko = mt * 16 + (ln & 15);
            wph[bid * 4096 + p] = (half_t)src[d * 32 + ko];
        }
    } else {
        const int total = N_NODES * D / 8;
        const int nb = gridDim.x - 44;
        for (int i = (bid - 44) * THREADS + t; i < total; i += nb * THREADS) {
            const float4* s = (const float4*)x + (size_t)i * 2;
            float4 a = s[0], b = s[1];
            f16x8 h8 = {(half_t)a.x, (half_t)a.y, (half_t)a.z, (half_t)a.w,
                        (half_t)b.x, (half_t)b.y, (half_t)b.z, (half_t)b.w};
            *((f16x8*)xh + i) = h8;
        }
    }
}

// -------------------- staging: slot SLOT -> buf (async DMA) -----------------
template<int SLOT>
__device__ __forceinline__ void stage_slot(const half_t* __restrict__ xh,
                                           const int (&rows)[4], const int4 (&nb4)[4],
                                           int base, char* buf, int lane)
{
    const int rr = lane >> 4;
    const int c = lane & 15;
#pragma unroll
    for (int i = 0; i < 4; ++i) {
        int row = rows[i];
        int src;
        if constexpr (SLOT == 0) {
            int node = base + row;
            src = (node >= N_NODES) ? (N_NODES - 1) : node;
        } else if constexpr (SLOT == 1) src = nb4[i].x;
        else if constexpr (SLOT == 2) src = nb4[i].y;
        else if constexpr (SLOT == 3) src = nb4[i].z;
        else                          src = nb4[i].w;
        const char* g = (const char*)xh + (size_t)src * 256 + ((c ^ (row & 7)) << 4);
        async_copy16(g, buf + (row - rr) * 256);   // lds dest: uniform + lane*16
    }
}

// ----------------------------- A-frag preload --------------------------------
__device__ __forceinline__ void load_af(int mid, const half_t* __restrict__ wph,
                                        int lane, f16x8 (&af)[8])
{
#pragma unroll
    for (int kt = 0; kt < 4; ++kt) {
        af[kt * 2]     = *(const f16x8*)(wph + ((mid * 8 + kt) * 64 + lane) * 8);
        af[kt * 2 + 1] = *(const f16x8*)(wph + ((mid * 8 + 4 + kt) * 64 + lane) * 8);
    }
}

// ------- 32(kout) x 64(node) x 128(d) projection from preloaded A-frags ------
__device__ __forceinline__ void proj_mfma(const f16x8 (&af)[8], const half_t* tile,
                                          int lane, f32x4 (&acc)[2][4])
{
    const int l15 = lane & 15, q = lane >> 4;
#pragma unroll
    for (int mt = 0; mt < 2; ++mt)
#pragma unroll
        for (int nt = 0; nt < 4; ++nt)
            acc[mt][nt] = (f32x4){0.f, 0.f, 0.f, 0.f};
#pragma unroll
    for (int kt = 0; kt < 4; ++kt) {
#pragma unroll
        for (int nt = 0; nt < 4; ++nt) {
            int row = nt * 16 + l15;
            int sq = (kt * 4 + q) ^ (row & 7);
            f16x8 b = *(const f16x8*)(tile + row * 128 + sq * 8);
            acc[0][nt] = __builtin_amdgcn_mfma_f32_16x16x32_f16(af[kt * 2], b, acc[0][nt], 0, 0, 0);
            acc[1][nt] = __builtin_amdgcn_mfma_f32_16x16x32_f16(af[kt * 2 + 1], b, acc[1][nt], 0, 0, 0);
        }
    }
}

// --------------------------- kernel 1: Q,K -> e, sums ------------------------
__global__ __launch_bounds__(THREADS, 3)
void knot_logits(const half_t* __restrict__ xh, const int* __restrict__ nbr,
                 const half_t* __restrict__ wph,
                 half_t* __restrict__ eh, float* __restrict__ sums_p)
{
    __shared__ __align__(16) char bufA[NPB * 256];
    __shared__ __align__(16) char bufB[NPB * 256];
    const int base = blockIdx.x * NPB;
    const int lane = threadIdx.x & 63;
    const int h = __builtin_amdgcn_readfirstlane((int)(threadIdx.x >> 6));
    const int l15 = lane & 15, rr = lane >> 4;

    int rows[4]; int4 nb4[4];
#pragma unroll
    for (int i = 0; i < 4; ++i) {
        rows[i] = h * 16 + i * 4 + rr;
        int node = base + rows[i];
        if (node >= N_NODES) node = N_NODES - 1;
        nb4[i] = ((const int4*)nbr)[node];
    }

    stage_slot<0>(xh, rows, nb4, base, bufA, lane);
    stage_slot<1>(xh, rows, nb4, base, bufB, lane);
    __syncthreads();

    f16x8 af[8];
    f32x4 qf[2][4], kf[2][4];
    load_af(h, wph, lane, af);
    proj_mfma(af, (const half_t*)bufA, lane, qf);          // Q from slot-0 tile

    auto slot = [&](auto rc) {
        constexpr int r = decltype(rc)::value;
        const half_t* cur = (const half_t*)((r & 1) ? bufB : bufA);
        char* nxt = ((r + 1) & 1) ? bufB : bufA;
        load_af(4 + h * 5 + r, wph, lane, af);             // older than DMAs
        if constexpr (r >= 1 && r <= 3) {
            __builtin_amdgcn_sched_barrier(0);             // keep af-loads first
            stage_slot<r + 1>(xh, rows, nb4, base, nxt, lane);
        }
        proj_mfma(af, cur, lane, kf);

        float esum = 0.f;
#pragma unroll
        for (int nt = 0; nt < 4; ++nt) {
            float p = 0.f;
#pragma unroll
            for (int mt = 0; mt < 2; ++mt)
#pragma unroll
                for (int j = 0; j < 4; ++j)
                    p += qf[mt][nt][j] * kf[mt][nt][j];
            p += __shfl_xor(p, 16, 64);
            p += __shfl_xor(p, 32, 64);
            int node = base + nt * 16 + l15;
            float e = (node < N_NODES) ? __expf(p * 0.17677669529663688f) : 0.f;
            if (rr == 0 && node < N_NODES)
                eh[(size_t)(h * 5 + r) * N_NODES + node] = (half_t)e;
            esum += e;
        }
        esum += __shfl_xor(esum, 1, 64);
        esum += __shfl_xor(esum, 2, 64);
        esum += __shfl_xor(esum, 4, 64);
        esum += __shfl_xor(esum, 8, 64);
        if (lane == 0)
            atomicAdd(&sums_p[(h * 5 + r) * 64 + (blockIdx.x & 63)], esum);
        __syncthreads();                 // drains prefetch (issued ~1 slot ago)
    };
    slot(ic<0>{}); slot(ic<1>{}); slot(ic<2>{}); slot(ic<3>{}); slot(ic<4>{});
}

// --------------------------- kernel 2: V -> Z -> out -------------------------
#define VS 67
__global__ __launch_bounds__(THREADS, 3)
void knot_out(const half_t* __restrict__ xh, const int* __restrict__ nbr,
              const half_t* __restrict__ wph, const half_t* __restrict__ eh,
              const float* __restrict__ sums_p, float* __restrict__ out)
{
    __shared__ __align__(16) char bufA[NPB * 256];
    __shared__ __align__(16) char bufB[NPB * 256];
    __shared__ float sums_s[20];
    const int base = blockIdx.x * NPB;
    const int lane = threadIdx.x & 63;
    const int h = __builtin_amdgcn_readfirstlane((int)(threadIdx.x >> 6));
    const int l15 = lane & 15, rr = lane >> 4, q = rr;

    // redundant per-block reduce of sums_p[20][64] (replaces reduce kernel)
#pragma unroll
    for (int i = 0; i < 5; ++i) {
        int hr = h * 5 + i;
        float v = sums_p[hr * 64 + lane];
        v += __shfl_xor(v, 1, 64);  v += __shfl_xor(v, 2, 64);
        v += __shfl_xor(v, 4, 64);  v += __shfl_xor(v, 8, 64);
        v += __shfl_xor(v, 16, 64); v += __shfl_xor(v, 32, 64);
        if (lane == 0) sums_s[hr] = v;
    }

    int rows[4]; int4 nb4[4];
#pragma unroll
    for (int i = 0; i < 4; ++i) {
        rows[i] = h * 16 + i * 4 + rr;
        int node = base + rows[i];
        if (node >= N_NODES) node = N_NODES - 1;
        nb4[i] = ((const int4*)nbr)[node];
    }

    stage_slot<0>(xh, rows, nb4, base, bufA, lane);
    stage_slot<1>(xh, rows, nb4, base, bufB, lane);
    __syncthreads();                                   // covers sums_s too

    float inv[5];
#pragma unroll
    for (int r = 0; r < 5; ++r) inv[r] = 1.0f / sums_s[h * 5 + r];

    f16x8 af[8];
    f32x4 z[2][4], vf[2][4];
#pragma unroll
    for (int mt = 0; mt < 2; ++mt)
#pragma unroll
        for (int nt = 0; nt < 4; ++nt)
            z[mt][nt] = (f32x4){0.f, 0.f, 0.f, 0.f};

    auto slot = [&](auto rc) {
        constexpr int r = decltype(rc)::value;
        const half_t* cur = (const half_t*)((r & 1) ? bufB : bufA);
        char* nxt = ((r + 1) & 1) ? bufB : bufA;
        load_af(24 + h * 5 + r, wph, lane, af);
        float ev[4];
#pragma unroll
        for (int nt = 0; nt < 4; ++nt) {
            int node = base + nt * 16 + l15;
            if (node >= N_NODES) node = N_NODES - 1;
            ev[nt] = (float)eh[(size_t)(h * 5 + r) * N_NODES + node];
        }
        if constexpr (r >= 1 && r <= 3) {
            __builtin_amdgcn_sched_barrier(0);
            stage_slot<r + 1>(xh, rows, nb4, base, nxt, lane);
        }
        proj_mfma(af, cur, lane, vf);
#pragma unroll
        for (int nt = 0; nt < 4; ++nt) {
            float w = ev[nt] * inv[r];
#pragma unroll
            for (int mt = 0; mt < 2; ++mt)
#pragma unroll
                for (int j = 0; j < 4; ++j)
                    z[mt][nt][j] += w * vf[mt][nt][j];
        }
        __syncthreads();
    };
    slot(ic<0>{}); slot(ic<1>{}); slot(ic<2>{}); slot(ic<3>{}); slot(ic<4>{});

    // ---- epilogue: 2 passes x 2 heads; head (h&1) uses bufA/bufB as zt ----
#pragma unroll 1
    for (int pass = 0; pass < 2; ++pass) {
        if (pass) __syncthreads();
        if ((h >> 1) == pass) {
            float* ztp = (float*)((h & 1) ? bufB : bufA);
#pragma unroll
            for (int mt = 0; mt < 2; ++mt)
#pragma unroll
                for (int nt = 0; nt < 4; ++nt)
#pragma unroll
                    for (int j = 0; j < 4; ++j) {
                        int v = mt * 16 + q * 4 + j;
                        ztp[v * VS + nt * 16 + l15] = z[mt][nt][j];
                    }
        }
        __syncthreads();
        const int row = threadIdx.x >> 2;
        const int c = threadIdx.x & 3;
        if (base + row < N_NODES) {
            float* dst = out + (size_t)(base + row) * D + pass * 64 + c * 16;
#pragma unroll
            for (int i4 = 0; i4 < 4; ++i4) {
                float4 v4;
#pragma unroll
                for (int e = 0; e < 4; ++e) {
                    int col = c * 16 + i4 * 4 + e;           // 0..63
                    const float* ztp = (const float*)((col & 32) ? bufB : bufA);
                    ((float*)&v4)[e] = ztp[(col & 31) * VS + row];
                }
                *(float4*)(dst + i4 * 4) = v4;
            }
        }
    }
}

// --------------------------------- launcher ---------------------------------
// ws layout (bytes): [0,5120) sums_p[20*64] | [8192,+4e6) eh f16[20*N]
//                    [4194304,+360448) wph | [4718592,+25.6e6) xh   ~30.3 MB
extern "C" void kernel_launch(void* const* d_in, const int* in_sizes, int n_in,
                              void* d_out, int out_size, void* d_ws, size_t ws_size,
                              hipStream_t stream)
{
    const float* x   = (const float*)d_in[0];
    const int*   nbr = (const int*)d_in[1];
    const float* w_q = (const float*)d_in[2];
    const float* w_k = (const float*)d_in[3];
    const float* w_v = (const float*)d_in[4];
    float* out = (float*)d_out;

    float*  sums_p = (float*)d_ws;
    half_t* eh     = (half_t*)((char*)d_ws + 8192);
    half_t* wph    = (half_t*)((char*)d_ws + 4194304);
    half_t* xh     = (half_t*)((char*)d_ws + 4718592);

    hipMemsetAsync(d_ws, 0, 5120, stream);
    prep<<<44 + 2048, THREADS, 0, stream>>>(x, w_q, w_k, w_v, xh, wph);
    knot_logits<<<NBLOCKS, THREADS, 0, stream>>>(xh, nbr, wph, eh, sums_p);
    knot_out<<<NBLOCKS, THREADS, 0, stream>>>(xh, nbr, wph, eh, sums_p, out);
}